// Round 4
// baseline (1058.572 us; speedup 1.0000x reference)
//
#include <hip/hip_runtime.h>

#define NB   32
#define NSUP 25
#define NC   512
#define NHW  196
#define NDK  128
#define NPT  4900      // NSUP*NHW
#define NPTP 4928      // sv p-dim padded to 77*64

typedef short  bf16x8 __attribute__((ext_vector_type(8)));
typedef float  f32x4  __attribute__((ext_vector_type(4)));
typedef unsigned short ushort;
typedef unsigned int   uint;
typedef ushort ushort4v __attribute__((ext_vector_type(4)));

static __device__ __forceinline__ ushort f2bf(float f) {
    union { float f; uint u; } v; v.f = f;
    uint r = v.u + 0x7fffu + ((v.u >> 16) & 1u);   // RNE
    return (ushort)(r >> 16);
}
static __device__ __forceinline__ f32x4 mfma16(bf16x8 a, bf16x8 b, f32x4 c) {
    return __builtin_amdgcn_mfma_f32_16x16x32_bf16(a, b, c, 0, 0, 0);
}

// ---------------------------------------------------------------------------
// k_cast: Wqk[128x512] + Wv[128x512] fp32 -> Wc[256x512] bf16
// ---------------------------------------------------------------------------
__global__ __launch_bounds__(256) void k_cast(
    const float* __restrict__ Wqk, const float* __restrict__ Wv,
    ushort* __restrict__ Wc)
{
    int i = blockIdx.x * 256 + threadIdx.x;            // float4 index < 32768
    const float* src = (i < 16384) ? Wqk : Wv;
    int j = (i < 16384) ? i : i - 16384;
    f32x4 v = *(const f32x4*)(src + (size_t)j * 4);
    ushort4v u;
    u[0] = f2bf(v[0]); u[1] = f2bf(v[1]); u[2] = f2bf(v[2]); u[3] = f2bf(v[3]);
    *(ushort4v*)(Wc + (size_t)i * 4) = u;
}

// ---------------------------------------------------------------------------
// k_proj: per (n, b): OUT[256 d][208 p-pad] = Wc[256x512] @ X[512x196]
// 8 waves = (dB 0..3: 64-d band) x (pg 0..1: p-half).  Swapped orientation:
// A = X-tile (row = p, from LDS, XOR-swizzled), B = Wc (col = d, global/L2).
// D-frag: col = l15 = d, rows = 4 consecutive p -> coalesced stores via LDS
// roundtrip.  Outputs: sk[b][p][d], qq[b][s][d], sv[b][d][p], qv[b][s][d] f32.
// ---------------------------------------------------------------------------
__global__ __launch_bounds__(512) void k_proj(
    const float* __restrict__ query, const float* __restrict__ supports,
    const ushort* __restrict__ Wc,
    ushort* __restrict__ sk, ushort* __restrict__ sv,
    ushort* __restrict__ qq, float* __restrict__ qv)
{
    __shared__ __align__(16) ushort Sb[15360];   // 30720 B: Xl / Kst / Vst
    const int n = blockIdx.x, b = blockIdx.y;
    const bool isq = (n == NSUP);
    const float* X = isq ? (query + (size_t)b * NC * NHW)
                         : (supports + (size_t)(b * NSUP + n) * NC * NHW);
    const int t = threadIdx.x;
    const int w = t >> 6, l = t & 63, l15 = l & 15, l4 = l >> 4;
    const int dB = w >> 1;     // 64-d band 0..3
    const int pg = w & 1;      // p-half
    const int NTw = 7 - pg;    // tiles: 7 in half 0 (p 0..111), 6 in half 1

    f32x4 acc[4][7];
#pragma unroll
    for (int mi = 0; mi < 4; ++mi)
#pragma unroll
        for (int nt = 0; nt < 7; ++nt) acc[mi][nt] = (f32x4){0.f, 0.f, 0.f, 0.f};

    for (int kt = 0; kt < NC; kt += 64) {
        if (kt) __syncthreads();
        // ---- stage X[kt..kt+64)[0..196) -> Xl[p][64 k] bf16, byte^=(p&7)<<4
        // task: (kp 0..31 k-pair, pp 0..97 p-pair), k-minor in lane for
        // conflict-spread writes; 16-lane p-runs keep global 128B-coalesced.
#pragma unroll
        for (int pass = 0; pass < 7; ++pass) {
            int idx = pass * 512 + t;
            if (idx < 3136) {
                int kq = idx & 3, rest = idx >> 2;
                int pp = rest % 98, kb = rest / 98;
                int kp = kb * 4 + kq;
                const float* src = X + (size_t)(kt + 2 * kp) * NHW + 2 * pp;
                float2 f0 = *(const float2*)src;
                float2 f1 = *(const float2*)(src + NHW);
#pragma unroll
                for (int j = 0; j < 2; ++j) {
                    int p = 2 * pp + j;
                    float a0 = j ? f0.y : f0.x;
                    float a1 = j ? f1.y : f1.x;
                    uint wd = (uint)f2bf(a0) | ((uint)f2bf(a1) << 16);
                    uint off = (uint)(p * 128 + kp * 4) ^ ((uint)(p & 7) << 4);
                    *(uint*)((char*)Sb + off) = wd;
                }
            }
        }
        __syncthreads();
        // ---- compute
#pragma unroll
        for (int kkh = 0; kkh < 2; ++kkh) {
            bf16x8 bw[4];
#pragma unroll
            for (int mi = 0; mi < 4; ++mi)
                bw[mi] = *(const bf16x8*)&Wc[(size_t)(dB * 64 + mi * 16 + l15) * NC
                                             + kt + kkh * 32 + l4 * 8];
#pragma unroll
            for (int nt = 0; nt < 7; ++nt) {
                if (nt < NTw) {
                    int p = (pg * 7 + nt) * 16 + l15;
                    uint off = (uint)(p * 128 + kkh * 64 + l4 * 16)
                               ^ ((uint)(p & 7) << 4);
                    bf16x8 ax = *(const bf16x8*)((char*)Sb + off);
#pragma unroll
                    for (int mi = 0; mi < 4; ++mi)
                        acc[mi][nt] = mfma16(ax, bw[mi], acc[mi][nt]);
                }
            }
        }
    }

    // ---- epilogue: 4 rounds (part K/V x p-half), LDS stage -> coalesced store
#pragma unroll 1
    for (int part = 0; part < 2; ++part) {
#pragma unroll 1
        for (int ph = 0; ph < 2; ++ph) {
            __syncthreads();
            const bool mywave = (pg == ph) && ((dB >> 1) == part);
            if (mywave) {
                const int dloc = (dB & 1) * 64;
                if (part == 0) {
                    // Kst [112 p][136 d] shorts, byte ^= (p&7)<<4
#pragma unroll
                    for (int mi = 0; mi < 4; ++mi)
#pragma unroll
                        for (int nt = 0; nt < 7; ++nt) {
                            if (nt < NTw) {
                                int d = dloc + mi * 16 + l15;
#pragma unroll
                                for (int r = 0; r < 4; ++r) {
                                    int p = nt * 16 + l4 * 4 + r;
                                    uint off = (uint)((p * 136 + d) * 2)
                                               ^ ((uint)(p & 7) << 4);
                                    *(ushort*)((char*)Sb + off) = f2bf(acc[mi][nt][r]);
                                }
                            }
                        }
                } else if (!isq) {
                    // Vst [128 d][120 p] shorts, byte ^= (d&7)<<4
#pragma unroll
                    for (int mi = 0; mi < 4; ++mi)
#pragma unroll
                        for (int nt = 0; nt < 7; ++nt) {
                            if (nt < NTw) {
                                int d = dloc + mi * 16 + l15;
                                int p = nt * 16 + l4 * 4;
                                ushort4v u;
#pragma unroll
                                for (int r = 0; r < 4; ++r) u[r] = f2bf(acc[mi][nt][r]);
                                uint off = (uint)((d * 120 + p) * 2)
                                           ^ ((uint)(d & 7) << 4);
                                *(ushort4v*)((char*)Sb + off) = u;
                            }
                        }
                } else {
                    // qv: direct fp32 stores (64-B runs across l15)
#pragma unroll
                    for (int mi = 0; mi < 4; ++mi)
#pragma unroll
                        for (int nt = 0; nt < 7; ++nt) {
                            if (nt < NTw) {
                                int d = dloc + mi * 16 + l15;
#pragma unroll
                                for (int r = 0; r < 4; ++r) {
                                    int p = (pg * 7 + nt) * 16 + l4 * 4 + r;
                                    if (p < NHW)
                                        qv[((size_t)b * NHW + p) * NDK + d] = acc[mi][nt][r];
                                }
                            }
                        }
                }
            }
            __syncthreads();
            if (part == 0) {
                // Kst -> sk (or qq): rows of 256 B, b128 coalesced
                for (int idx = t; idx < 112 * 16; idx += 512) {
                    int row = idx >> 4, c = idx & 15;
                    int pimg = ph * 112 + row;
                    if (pimg < NHW) {
                        uint off = (uint)(row * 272 + c * 16) ^ ((uint)(row & 7) << 4);
                        bf16x8 vv = *(const bf16x8*)((char*)Sb + off);
                        ushort* dst = isq
                            ? &qq[((size_t)b * NHW + pimg) * NDK + c * 8]
                            : &sk[((size_t)b * NPT + n * NHW + pimg) * NDK + c * 8];
                        *(bf16x8*)dst = vv;
                    }
                }
            } else if (!isq) {
                // Vst -> sv: 224-B runs per d-row (b64 pairs: n*196 base is
                // only 8-B aligned)
                int nch = (ph == 0) ? 14 : 11;
                for (int idx = t; idx < 128 * nch; idx += 512) {
                    int d = idx / nch, c = idx - d * nch;
                    int pl = c * 8;
                    int pimg = ph * 112 + pl;
                    uint off = (uint)((d * 120 + pl) * 2) ^ ((uint)(d & 7) << 4);
                    ushort* dst = &sv[((size_t)b * NDK + d) * NPTP
                                      + (size_t)n * NHW + pimg];
                    if (pimg + 7 < NHW) {
                        ushort4v v0 = *(const ushort4v*)((char*)Sb + off);
                        ushort4v v1 = *(const ushort4v*)((char*)Sb + off + 8);
                        *(ushort4v*)dst = v0;
                        *(ushort4v*)(dst + 4) = v1;
                    } else if (pimg < NHW) {       // pimg 192..195
                        ushort4v v0 = *(const ushort4v*)((char*)Sb + off);
                        *(ushort4v*)dst = v0;
                    }
                }
            }
        }
    }
}

// ---------------------------------------------------------------------------
// k_attn: fused QK^T + fixed-shift softmax + PV + distance.  grid = 416
// blocks (b-to-XCD affine), 256 thr / 4 waves.  Per chunk of 64 p:
// wave w: S^T[16p (w)][16s] = sk-rows x Q-cols -> exp(x-60), mask p>=4900,
// pack bf16 -> Pl[16 s][64 p] -> PV: O[16 s][32 d (w)] += P x sv.
// ---------------------------------------------------------------------------
__global__ __launch_bounds__(256) void k_attn(
    const ushort* __restrict__ qq, const ushort* __restrict__ sk,
    const ushort* __restrict__ sv, const float* __restrict__ qv,
    float* __restrict__ out)
{
    __shared__ __align__(16) ushort Pl[16 * 80];
    __shared__ float rsP[4][16];
    __shared__ float rinv[16];
    __shared__ float wred[4];
    const int bid = blockIdx.x;
    const int xcd = bid & 7, slot = bid >> 3;     // keep each b's 13 blocks
    const int b = xcd + 8 * (slot & 3);           // on one XCD for K/V L2 reuse
    const int st = slot >> 2;
    const int s0 = st * 16;
    const int t = threadIdx.x;
    const int w = t >> 6, l = t & 63, l15 = l & 15, l4 = l >> 4;

    // hoisted Q B-frags (col = s, k-octet = d)
    const int sq = min(s0 + l15, NHW - 1);
    bf16x8 qf[4];
#pragma unroll
    for (int ks = 0; ks < 4; ++ks)
        qf[ks] = *(const bf16x8*)&qq[((size_t)b * NHW + sq) * NDK + ks * 32 + l4 * 8];

    f32x4 oacc[2];
    oacc[0] = (f32x4){0.f, 0.f, 0.f, 0.f};
    oacc[1] = (f32x4){0.f, 0.f, 0.f, 0.f};
    float psum = 0.f;

    for (int ch = 0; ch < 77; ++ch) {
        const int p0 = ch * 64;
        // ---- QK^T (A = sk rows p)
        const int pa = min(p0 + w * 16 + l15, NPT - 1);
        const ushort* arow = &sk[((size_t)b * NPT + pa) * NDK + l4 * 8];
        f32x4 sacc = (f32x4){0.f, 0.f, 0.f, 0.f};
#pragma unroll
        for (int ks = 0; ks < 4; ++ks)
            sacc = mfma16(*(const bf16x8*)(arow + ks * 32), qf[ks], sacc);
        // ---- exp, mask dead p, psum, pack  (lane: s = l15, p = .. + l4*4+r)
        ushort4v u;
#pragma unroll
        for (int r = 0; r < 4; ++r) {
            int p = p0 + w * 16 + l4 * 4 + r;
            float e = (p < NPT) ? __expf(sacc[r] - 60.f) : 0.f;
            psum += e;
            u[r] = f2bf(e);
        }
        *(ushort4v*)&Pl[l15 * 80 + w * 16 + l4 * 4] = u;
        __syncthreads();
        // ---- PV (A = Pl rows s, B = sv cols d)
        bf16x8 a0 = *(const bf16x8*)&Pl[l15 * 80 + l4 * 8];
        bf16x8 a1 = *(const bf16x8*)&Pl[l15 * 80 + 32 + l4 * 8];
#pragma unroll
        for (int dt = 0; dt < 2; ++dt) {
            int d = w * 32 + dt * 16 + l15;
            const ushort* svd = &sv[((size_t)b * NDK + d) * NPTP + p0 + l4 * 8];
            oacc[dt] = mfma16(a0, *(const bf16x8*)svd, oacc[dt]);
            oacc[dt] = mfma16(a1, *(const bf16x8*)(svd + 32), oacc[dt]);
        }
        __syncthreads();
    }

    // ---- rowsum (lane psum is for s = l15; fold l4 groups)
    psum += __shfl_down(psum, 32, 64);
    psum += __shfl_down(psum, 16, 64);
    if (l < 16) rsP[w][l] = psum;
    __syncthreads();
    if (t < 16) rinv[t] = 1.0f / (rsP[0][t] + rsP[1][t] + rsP[2][t] + rsP[3][t]);
    __syncthreads();

    // ---- distance epilogue (O-frag: col = l15 = d, rows = s = l4*4+r)
    float part = 0.f;
#pragma unroll
    for (int dt = 0; dt < 2; ++dt) {
        int d = w * 32 + dt * 16 + l15;
#pragma unroll
        for (int r = 0; r < 4; ++r) {
            int s = l4 * 4 + r;
            int sg = s0 + s;
            if (sg < NHW) {
                float o = oacc[dt][r] * rinv[s];
                float q = qv[((size_t)b * NHW + sg) * NDK + d];
                float df = q - o;
                part = fmaf(df, df, part);
            }
        }
    }
#pragma unroll
    for (int off = 32; off > 0; off >>= 1) part += __shfl_down(part, off, 64);
    if (l == 0) wred[w] = part;
    __syncthreads();
    if (t == 0)
        atomicAdd(out, (wred[0] + wred[1] + wred[2] + wred[3]) * (1.0f / 196.0f));
}

// ---------------------------------------------------------------------------
extern "C" void kernel_launch(void* const* d_in, const int* in_sizes, int n_in,
                              void* d_out, int out_size, void* d_ws, size_t ws_size,
                              hipStream_t stream)
{
    const float* query    = (const float*)d_in[0];
    const float* supports = (const float*)d_in[1];
    const float* Wqk      = (const float*)d_in[2];
    const float* Wv       = (const float*)d_in[3];
    float* out = (float*)d_out;

    char* ws = (char*)d_ws;
    ushort* Wc = (ushort*)ws;  ws += (size_t)256 * NC * 2;
    ushort* sk = (ushort*)ws;  ws += (size_t)NB * NPT * NDK * 2;
    ushort* sv = (ushort*)ws;  ws += (size_t)NB * NDK * NPTP * 2;
    ushort* qq = (ushort*)ws;  ws += (size_t)NB * NHW * NDK * 2;
    float*  qv = (float*)ws;

    hipMemsetAsync(d_out, 0, (size_t)out_size * sizeof(float), stream);
    k_cast<<<128, 256, 0, stream>>>(Wqk, Wv, Wc);
    k_proj<<<dim3(NSUP + 1, NB), 512, 0, stream>>>(query, supports, Wc,
                                                   sk, sv, qq, qv);
    k_attn<<<416, 256, 0, stream>>>(qq, sk, sv, qv, out);
}

// Round 6
// 1003.729 us; speedup vs baseline: 1.0546x; 1.0546x over previous
//
#include <hip/hip_runtime.h>

#define NB   32
#define NSUP 25
#define NC   512
#define NHW  196
#define NDK  128
#define NPT  4900      // NSUP*NHW
#define NPTP 4928      // sv p-dim padded to 77*64

typedef short  bf16x8 __attribute__((ext_vector_type(8)));
typedef float  f32x4  __attribute__((ext_vector_type(4)));
typedef unsigned short ushort;
typedef unsigned int   uint;
typedef ushort ushort4v __attribute__((ext_vector_type(4)));

static __device__ __forceinline__ ushort f2bf(float f) {
    union { float f; uint u; } v; v.f = f;
    uint r = v.u + 0x7fffu + ((v.u >> 16) & 1u);   // RNE
    return (ushort)(r >> 16);
}
static __device__ __forceinline__ f32x4 mfma16(bf16x8 a, bf16x8 b, f32x4 c) {
    return __builtin_amdgcn_mfma_f32_16x16x32_bf16(a, b, c, 0, 0, 0);
}

// ---------------------------------------------------------------------------
// k_cast: Wqk[128x512] + Wv[128x512] fp32 -> Wc[256x512] bf16
// ---------------------------------------------------------------------------
__global__ __launch_bounds__(256) void k_cast(
    const float* __restrict__ Wqk, const float* __restrict__ Wv,
    ushort* __restrict__ Wc)
{
    int i = blockIdx.x * 256 + threadIdx.x;            // float4 index < 32768
    const float* src = (i < 16384) ? Wqk : Wv;
    int j = (i < 16384) ? i : i - 16384;
    f32x4 v = *(const f32x4*)(src + (size_t)j * 4);
    ushort4v u;
    u[0] = f2bf(v[0]); u[1] = f2bf(v[1]); u[2] = f2bf(v[2]); u[3] = f2bf(v[3]);
    *(ushort4v*)(Wc + (size_t)i * 4) = u;
}

// ---------------------------------------------------------------------------
// k_proj: per (n, b): OUT[256 d][196 p] = Wc[256x512] @ X[512x196]
// 1024 thr = 16 waves = (dB 0..7: 32-d band) x (pg 0..1: p-half).
// acc[2][7] = 56 VGPR/thread (no spill, vs R4's 112).  X staged ONCE per
// block into Xl[196][64k] bf16 (25 KB, XOR (p&7)<<4 swizzle).  T14 split:
// global loads for kt+1 issued into regs before compute(kt).
// A = X rows p, B = Wc cols d -> D frag rows = 4 consecutive p, col = d.
// Epilogue: LDS roundtrip, coalesced stores.  Vst UNSWIZZLED (R4's XOR on
// the 240-B-stride Vst was non-bijective -> sv corruption -> absmax 64).
// ---------------------------------------------------------------------------
__global__ __launch_bounds__(1024) void k_proj(
    const float* __restrict__ query, const float* __restrict__ supports,
    const ushort* __restrict__ Wc,
    ushort* __restrict__ sk, ushort* __restrict__ sv,
    ushort* __restrict__ qq, float* __restrict__ qv)
{
    __shared__ __align__(16) ushort Sb[15360];   // 30720 B: Xl / Kst / Vst
    const int n = blockIdx.x, b = blockIdx.y;
    const bool isq = (n == NSUP);
    const float* X = isq ? (query + (size_t)b * NC * NHW)
                         : (supports + (size_t)(b * NSUP + n) * NC * NHW);
    const int t = threadIdx.x;
    const int w = t >> 6, l = t & 63, l15 = l & 15, l4 = l >> 4;
    const int dB = w >> 1;          // 32-d band 0..7
    const int pg = w & 1;           // p-half
    const int ntw = 7 - pg;         // 7 tiles (p 0..112) or 6 (p 112..196+pad)

    f32x4 acc[2][7];
#pragma unroll
    for (int mi = 0; mi < 2; ++mi)
#pragma unroll
        for (int nt = 0; nt < 7; ++nt) acc[mi][nt] = (f32x4){0.f, 0.f, 0.f, 0.f};

    // staging tasks: 3136 = (kp 0..31 k-pair) x (pp 0..97 p-pair); kq=idx&3
    // keeps 4-way-max LDS bank spread while 16-lane pp runs coalesce global.
    float2 g0[4], g1[4];
#define LOADX(KT)                                                            \
    do {                                                                     \
        _Pragma("unroll")                                                    \
        for (int ps = 0; ps < 4; ++ps) {                                     \
            int idx = ps * 1024 + t;                                         \
            if (idx < 3136) {                                                \
                int kq = idx & 3, rest = idx >> 2;                           \
                int pp = rest % 98, kb = rest / 98;                          \
                int kp = kb * 4 + kq;                                        \
                const float* src = X + (size_t)((KT) + 2 * kp) * NHW + 2 * pp;\
                g0[ps] = *(const float2*)src;                                \
                g1[ps] = *(const float2*)(src + NHW);                        \
            }                                                                \
        }                                                                    \
    } while (0)

    LOADX(0);
    for (int kt = 0; kt < NC; kt += 64) {
        __syncthreads();                     // compute(kt-1) done reading Xl
        // ---- write staged regs -> Xl[p][64 k], byte ^= (p&7)<<4
#pragma unroll
        for (int ps = 0; ps < 4; ++ps) {
            int idx = ps * 1024 + t;
            if (idx < 3136) {
                int kq = idx & 3, rest = idx >> 2;
                int pp = rest % 98, kb = rest / 98;
                int kp = kb * 4 + kq;
                float2 f0 = g0[ps], f1 = g1[ps];
#pragma unroll
                for (int j = 0; j < 2; ++j) {
                    int p = 2 * pp + j;
                    uint wd = (uint)f2bf(j ? f0.y : f0.x)
                              | ((uint)f2bf(j ? f1.y : f1.x) << 16);
                    uint off = (uint)(p * 128 + kp * 4) ^ ((uint)(p & 7) << 4);
                    *(uint*)((char*)Sb + off) = wd;
                }
            }
        }
        __syncthreads();
        if (kt + 64 < NC) LOADX(kt + 64);    // T14: overlap with compute below
        // ---- compute
        bf16x8 bw[2][2];
#pragma unroll
        for (int kkh = 0; kkh < 2; ++kkh)
#pragma unroll
            for (int mi = 0; mi < 2; ++mi)
                bw[kkh][mi] = *(const bf16x8*)&Wc[
                    (size_t)(dB * 32 + mi * 16 + l15) * NC + kt + kkh * 32 + l4 * 8];
#pragma unroll
        for (int kkh = 0; kkh < 2; ++kkh) {
#pragma unroll
            for (int nt = 0; nt < 7; ++nt) {
                if (nt < ntw) {
                    int p = pg * 112 + nt * 16 + l15;   // may reach 207: pad-read in Sb
                    uint off = (uint)(p * 128 + kkh * 64 + l4 * 16)
                               ^ ((uint)(p & 7) << 4);
                    bf16x8 ax = *(const bf16x8*)((char*)Sb + off);
                    acc[0][nt] = mfma16(ax, bw[kkh][0], acc[0][nt]);
                    acc[1][nt] = mfma16(ax, bw[kkh][1], acc[1][nt]);
                }
            }
        }
    }

    // ---- epilogue: rounds (part K/V x ph p-half), LDS stage -> coalesced
#pragma unroll 1
    for (int part = 0; part < 2; ++part) {
#pragma unroll 1
        for (int ph = 0; ph < 2; ++ph) {
            __syncthreads();
            const int plim = ph ? 84 : 112;
            if (part == 0) {
                if (dB < 4 && pg == ph) {
                    // Kst [112 p][136 d] shorts, byte ^= (p&7)<<4 (bijective)
#pragma unroll
                    for (int mi = 0; mi < 2; ++mi) {
                        int d = dB * 32 + mi * 16 + l15;
#pragma unroll
                        for (int nt = 0; nt < 7; ++nt) {
                            if (nt < ntw) {
#pragma unroll
                                for (int r = 0; r < 4; ++r) {
                                    int pl = nt * 16 + l4 * 4 + r;
                                    if (pl < plim) {
                                        uint off = (uint)((pl * 136 + d) * 2)
                                                   ^ ((uint)(pl & 7) << 4);
                                        *(ushort*)((char*)Sb + off) =
                                            f2bf(acc[mi][nt][r]);
                                    }
                                }
                            }
                        }
                    }
                }
            } else {
                if (dB >= 4 && pg == ph) {
                    int dvb = (dB - 4) * 32;
                    if (!isq) {
                        // Vst [128 d][120 p] shorts, NO swizzle
#pragma unroll
                        for (int mi = 0; mi < 2; ++mi) {
                            int dv = dvb + mi * 16 + l15;
#pragma unroll
                            for (int nt = 0; nt < 7; ++nt) {
                                if (nt < ntw) {
                                    int pl = nt * 16 + l4 * 4;
                                    if (pl < plim) {
                                        ushort4v u;
#pragma unroll
                                        for (int r = 0; r < 4; ++r)
                                            u[r] = f2bf(acc[mi][nt][r]);
                                        *(ushort4v*)((char*)Sb
                                            + (uint)((dv * 120 + pl) * 2)) = u;
                                    }
                                }
                            }
                        }
                    } else {
                        // qv: direct fp32 stores (16 consecutive d = 64-B runs)
#pragma unroll
                        for (int mi = 0; mi < 2; ++mi) {
                            int dv = dvb + mi * 16 + l15;
#pragma unroll
                            for (int nt = 0; nt < 7; ++nt) {
                                if (nt < ntw) {
#pragma unroll
                                    for (int r = 0; r < 4; ++r) {
                                        int p = ph * 112 + nt * 16 + l4 * 4 + r;
                                        if (p < NHW)
                                            qv[((size_t)b * NHW + p) * NDK + dv]
                                                = acc[mi][nt][r];
                                    }
                                }
                            }
                        }
                    }
                }
            }
            __syncthreads();
            if (part == 0) {
                // Kst -> sk/qq: 256-B aligned full rows
                for (int idx = t; idx < 112 * 16; idx += 1024) {
                    int row = idx >> 4, c = idx & 15;
                    if (row < plim) {
                        int pimg = ph * 112 + row;
                        uint off = (uint)(row * 272 + c * 16)
                                   ^ ((uint)(row & 7) << 4);
                        bf16x8 vv = *(const bf16x8*)((char*)Sb + off);
                        ushort* dst = isq
                            ? &qq[((size_t)b * NHW + pimg) * NDK + c * 8]
                            : &sk[((size_t)b * NPT + n * NHW + pimg) * NDK + c * 8];
                        *(bf16x8*)dst = vv;
                    }
                }
            } else if (!isq) {
                // Vst -> sv: 224/168-B runs per d-row
                const int nch = ph ? 11 : 14;
                for (int idx = t; idx < 128 * nch; idx += 1024) {
                    int d, c;
                    if (ph == 0) { d = idx / 14; c = idx - d * 14; }
                    else         { d = idx / 11; c = idx - d * 11; }
                    int pl = c * 8;
                    int pimg = ph * 112 + pl;
                    uint off = (uint)((d * 120 + pl) * 2);
                    ushort* dst = &sv[((size_t)b * NDK + d) * NPTP
                                      + (size_t)n * NHW + pimg];
                    if (pimg + 7 < NHW) {
                        ushort4v v0 = *(const ushort4v*)((char*)Sb + off);
                        ushort4v v1 = *(const ushort4v*)((char*)Sb + off + 8);
                        *(ushort4v*)dst = v0;
                        *(ushort4v*)(dst + 4) = v1;
                    } else if (pimg < NHW) {       // pimg 192..195
                        ushort4v v0 = *(const ushort4v*)((char*)Sb + off);
                        *(ushort4v*)dst = v0;
                    }
                }
            }
        }
    }
}

// ---------------------------------------------------------------------------
// k_attn: fused QK^T + fixed-shift softmax (exp(x-60), exact after norm) +
// PV + distance.  grid 416 (b XCD-affine), 256 thr / 4 waves.  Software
// pipeline: chunk ch+1's 8 K/V frags prefetched into regs during chunk ch;
// Pl double-buffered -> ONE barrier per chunk.
// ---------------------------------------------------------------------------
__global__ __launch_bounds__(256) void k_attn(
    const ushort* __restrict__ qq, const ushort* __restrict__ sk,
    const ushort* __restrict__ sv, const float* __restrict__ qv,
    float* __restrict__ out)
{
    __shared__ __align__(16) ushort Pl[2][16 * 80];
    __shared__ float rsP[4][16];
    __shared__ float rinv[16];
    __shared__ float wred[4];
    const int bid = blockIdx.x;
    const int b = (bid & 7) + 8 * ((bid >> 3) & 3);   // 13 blocks/b -> one XCD
    const int s0 = (bid >> 5) * 16;
    const int t = threadIdx.x;
    const int w = t >> 6, l = t & 63, l15 = l & 15, l4 = l >> 4;

    const ushort* skb = sk + (size_t)b * NPT * NDK;
    const ushort* svb = sv + (size_t)b * NDK * NPTP;

    // hoisted Q B-frags (col = s, k-octet = d)
    const int sq = min(s0 + l15, NHW - 1);
    bf16x8 qf[4];
#pragma unroll
    for (int ks = 0; ks < 4; ++ks)
        qf[ks] = *(const bf16x8*)&qq[((size_t)b * NHW + sq) * NDK + ks * 32 + l4 * 8];

    // prefetch chunk 0 frags
    bf16x8 ka[4], va[4];
    {
        const ushort* ar = skb + (size_t)(w * 16 + l15) * NDK + l4 * 8;
#pragma unroll
        for (int ks = 0; ks < 4; ++ks) ka[ks] = *(const bf16x8*)(ar + ks * 32);
#pragma unroll
        for (int dt = 0; dt < 2; ++dt) {
            const ushort* vr = svb + (size_t)(w * 32 + dt * 16 + l15) * NPTP + l4 * 8;
            va[2 * dt]     = *(const bf16x8*)vr;
            va[2 * dt + 1] = *(const bf16x8*)(vr + 32);
        }
    }

    f32x4 oacc[2];
    oacc[0] = (f32x4){0.f, 0.f, 0.f, 0.f};
    oacc[1] = (f32x4){0.f, 0.f, 0.f, 0.f};
    float psum = 0.f;

    for (int ch = 0; ch < 77; ++ch) {
        const int p0 = ch * 64;
        // ---- issue next chunk's loads (overlap with everything below)
        bf16x8 kn[4], vn[4];
        if (ch < 76) {
            const int pa = min(p0 + 64 + w * 16 + l15, NPT - 1);
            const ushort* ar = skb + (size_t)pa * NDK + l4 * 8;
#pragma unroll
            for (int ks = 0; ks < 4; ++ks) kn[ks] = *(const bf16x8*)(ar + ks * 32);
#pragma unroll
            for (int dt = 0; dt < 2; ++dt) {
                const ushort* vr = svb + (size_t)(w * 32 + dt * 16 + l15) * NPTP
                                   + p0 + 64 + l4 * 8;
                vn[2 * dt]     = *(const bf16x8*)vr;
                vn[2 * dt + 1] = *(const bf16x8*)(vr + 32);
            }
        }
        // ---- QK^T: S^T[16 p (w)][16 s]
        f32x4 sacc = (f32x4){0.f, 0.f, 0.f, 0.f};
#pragma unroll
        for (int ks = 0; ks < 4; ++ks) sacc = mfma16(ka[ks], qf[ks], sacc);
        // ---- exp, mask dead p, psum, pack (lane: s = l15, p = w*16+l4*4+r)
        ushort4v u;
#pragma unroll
        for (int r = 0; r < 4; ++r) {
            int p = p0 + w * 16 + l4 * 4 + r;
            float e = __expf(sacc[r] - 60.f);
            e = (p < NPT) ? e : 0.f;
            psum += e;
            u[r] = f2bf(e);
        }
        *(ushort4v*)&Pl[ch & 1][l15 * 80 + w * 16 + l4 * 4] = u;
        __syncthreads();
        // ---- PV: O[16 s][32 d (w)] += P x V
        bf16x8 a0 = *(const bf16x8*)&Pl[ch & 1][l15 * 80 + l4 * 8];
        bf16x8 a1 = *(const bf16x8*)&Pl[ch & 1][l15 * 80 + 32 + l4 * 8];
        oacc[0] = mfma16(a0, va[0], oacc[0]);
        oacc[0] = mfma16(a1, va[1], oacc[0]);
        oacc[1] = mfma16(a0, va[2], oacc[1]);
        oacc[1] = mfma16(a1, va[3], oacc[1]);
        if (ch < 76) {
#pragma unroll
            for (int i = 0; i < 4; ++i) { ka[i] = kn[i]; va[i] = vn[i]; }
        }
    }

    // ---- rowsum (lane psum is for s = l15; fold l4 groups, then waves)
    psum += __shfl_down(psum, 32, 64);
    psum += __shfl_down(psum, 16, 64);
    if (l < 16) rsP[w][l] = psum;
    __syncthreads();
    if (t < 16) rinv[t] = 1.0f / (rsP[0][t] + rsP[1][t] + rsP[2][t] + rsP[3][t]);
    __syncthreads();

    // ---- distance epilogue (O-frag: col = l15 = d, rows = s = l4*4+r)
    float part = 0.f;
#pragma unroll
    for (int dt = 0; dt < 2; ++dt) {
        int d = w * 32 + dt * 16 + l15;
#pragma unroll
        for (int r = 0; r < 4; ++r) {
            int s = l4 * 4 + r;
            int sg = s0 + s;
            if (sg < NHW) {
                float o = oacc[dt][r] * rinv[s];
                float q = qv[((size_t)b * NHW + sg) * NDK + d];
                float df = q - o;
                part = fmaf(df, df, part);
            }
        }
    }
#pragma unroll
    for (int off = 32; off > 0; off >>= 1) part += __shfl_down(part, off, 64);
    if (l == 0) wred[w] = part;
    __syncthreads();
    if (t == 0)
        atomicAdd(out, (wred[0] + wred[1] + wred[2] + wred[3]) * (1.0f / 196.0f));
}

// ---------------------------------------------------------------------------
extern "C" void kernel_launch(void* const* d_in, const int* in_sizes, int n_in,
                              void* d_out, int out_size, void* d_ws, size_t ws_size,
                              hipStream_t stream)
{
    const float* query    = (const float*)d_in[0];
    const float* supports = (const float*)d_in[1];
    const float* Wqk      = (const float*)d_in[2];
    const float* Wv       = (const float*)d_in[3];
    float* out = (float*)d_out;

    char* ws = (char*)d_ws;
    ushort* Wc = (ushort*)ws;  ws += (size_t)256 * NC * 2;
    ushort* sk = (ushort*)ws;  ws += (size_t)NB * NPT * NDK * 2;
    ushort* sv = (ushort*)ws;  ws += (size_t)NB * NDK * NPTP * 2;
    ushort* qq = (ushort*)ws;  ws += (size_t)NB * NHW * NDK * 2;
    float*  qv = (float*)ws;

    hipMemsetAsync(d_out, 0, (size_t)out_size * sizeof(float), stream);
    k_cast<<<128, 256, 0, stream>>>(Wqk, Wv, Wc);
    k_proj<<<dim3(NSUP + 1, NB), 1024, 0, stream>>>(query, supports, Wc,
                                                    sk, sv, qq, qv);
    k_attn<<<416, 256, 0, stream>>>(qq, sk, sv, qv, out);
}